// Round 2
// baseline (87.075 us; speedup 1.0000x reference)
//
#include <hip/hip_runtime.h>
#include <hip/hip_bf16.h>

#define ALPHA 0.2f
#define NEG_BIG -1e12f

constexpr int B_ = 8, N_ = 2048, C_ = 128;
constexpr int IB = 16, JB = 128, NJT = N_ / JB;   // 16 j-tiles

typedef __attribute__((ext_vector_type(8))) short short8;
typedef __attribute__((ext_vector_type(8))) unsigned short ushort8;
typedef __attribute__((ext_vector_type(4))) float f32x4;

__device__ __forceinline__ unsigned short f2bf(float f) {
    unsigned int u = __float_as_uint(f);
    u += 0x7fffu + ((u >> 16) & 1u);
    return (unsigned short)(u >> 16);
}

__device__ __forceinline__ unsigned int cvtpk_bf16(float lo, float hi) {
    unsigned int r;
    asm("v_cvt_pk_bf16_f32 %0, %1, %2" : "=v"(r) : "v"(lo), "v"(hi));
    return r;
}

// ---------------------------------------------------------------------------
// Kernel 1: hidden = x @ W (f32, exact), emit hiddenT bf16 [B, C, N] and
// attn1/attn2 = hidden @ a (f32, exact).  64 rows per block, 256 threads.
// ---------------------------------------------------------------------------
__global__ __launch_bounds__(256) void k1_hidden(
    const float* __restrict__ x, const float* __restrict__ W,
    const float* __restrict__ a, unsigned short* __restrict__ hT,
    float* __restrict__ at1, float* __restrict__ at2)
{
    __shared__ float xs[64][C_];   // 32 KB
    __shared__ float Ws[C_][C_];   // 64 KB
    const int tid = threadIdx.x;
    const int row0 = blockIdx.x * 64;   // global row = b*N + n

    {
        const float4* xsrc = (const float4*)(x + (size_t)row0 * C_);
        float4* xdst = (float4*)&xs[0][0];
        for (int i = tid; i < 64 * C_ / 4; i += 256) xdst[i] = xsrc[i];
        const float4* wsrc = (const float4*)W;
        float4* wdst = (float4*)&Ws[0][0];
        for (int i = tid; i < C_ * C_ / 4; i += 256) wdst[i] = wsrc[i];
    }
    __syncthreads();

    const int tr = tid >> 5, tc = tid & 31;
    const int r0 = tr * 8, c0 = tc * 4;

    float acc[8][4];
#pragma unroll
    for (int i = 0; i < 8; ++i)
#pragma unroll
        for (int j = 0; j < 4; ++j) acc[i][j] = 0.f;

    for (int k = 0; k < C_; k += 4) {
        float4 w0 = *(const float4*)&Ws[k + 0][c0];
        float4 w1 = *(const float4*)&Ws[k + 1][c0];
        float4 w2 = *(const float4*)&Ws[k + 2][c0];
        float4 w3 = *(const float4*)&Ws[k + 3][c0];
#pragma unroll
        for (int rr = 0; rr < 8; ++rr) {
            float4 xv = *(const float4*)&xs[r0 + rr][k];
            acc[rr][0] += xv.x * w0.x + xv.y * w1.x + xv.z * w2.x + xv.w * w3.x;
            acc[rr][1] += xv.x * w0.y + xv.y * w1.y + xv.z * w2.y + xv.w * w3.y;
            acc[rr][2] += xv.x * w0.z + xv.y * w1.z + xv.z * w2.z + xv.w * w3.z;
            acc[rr][3] += xv.x * w0.w + xv.y * w1.w + xv.z * w2.w + xv.w * w3.w;
        }
    }

    // scores: reduce h . a over the 32 tc-lanes (each holds 4 cols)
    float av0[4], av1[4];
#pragma unroll
    for (int cc = 0; cc < 4; ++cc) {
        av0[cc] = a[(c0 + cc) * 2 + 0];
        av1[cc] = a[(c0 + cc) * 2 + 1];
    }
#pragma unroll
    for (int rr = 0; rr < 8; ++rr) {
        float s1 = acc[rr][0] * av0[0] + acc[rr][1] * av0[1] +
                   acc[rr][2] * av0[2] + acc[rr][3] * av0[3];
        float s2 = acc[rr][0] * av1[0] + acc[rr][1] * av1[1] +
                   acc[rr][2] * av1[2] + acc[rr][3] * av1[3];
#pragma unroll
        for (int off = 1; off < 32; off <<= 1) {
            s1 += __shfl_xor(s1, off);
            s2 += __shfl_xor(s2, off);
        }
        if (tc == 0) {
            at1[row0 + r0 + rr] = s1;
            at2[row0 + r0 + rr] = s2;
        }
    }

    // hiddenT bf16: hT[b][c][n]; this thread's 8 rows are consecutive n.
    const int b = row0 >> 11;           // /N_
    const int n0 = row0 & (N_ - 1);
#pragma unroll
    for (int cc = 0; cc < 4; ++cc) {
        ushort8 hv;
#pragma unroll
        for (int rr = 0; rr < 8; ++rr) hv[rr] = f2bf(acc[rr][cc]);
        *(ushort8*)(hT + ((size_t)b * C_ + c0 + cc) * N_ + n0 + r0) = hv;
    }
}

// ---------------------------------------------------------------------------
// Kernel 2: flash-style masked softmax + PV via bf16 MFMA.
// IB=16 rows/block, JB=128 j-tile, 256 threads (4 waves, c-split 32 each).
// Double-buffered P + srow -> ONE barrier per tile.
// ---------------------------------------------------------------------------
__global__ __launch_bounds__(256, 4) void k2_attn(
    const int* __restrict__ adj, const unsigned short* __restrict__ hT,
    const float* __restrict__ at1, const float* __restrict__ at2,
    const float* __restrict__ bias, float* __restrict__ out)
{
    __shared__ unsigned short P[2][IB][JB + 8];   // 2 x 16 x 136 bf16 (8.7 KB)
    __shared__ float at2s[N_];                    // 8 KB: whole at2 row for batch
    __shared__ float mrow[IB], lrow[IB], srow[2][IB];

    const int tid = threadIdx.x;
    const int b  = blockIdx.x >> 7;               // N_/IB = 128 i-tiles per batch
    const int i0 = (blockIdx.x & 127) * IB;

    // stage at2[b, :] into LDS (2048 floats)
    {
        const float4* src = (const float4*)(at2 + (size_t)b * N_);
        float4* dst = (float4*)at2s;
        dst[tid]       = src[tid];
        dst[tid + 256] = src[tid + 256];
    }
    if (tid < IB) { mrow[tid] = -3e38f; lrow[tid] = 0.f; }

    // softmax-side ids: 16 threads per row, 8 j each
    const int r  = tid >> 4;                      // 0..15
    const int jl = tid & 15;                      // 0..15
    const float a1 = at1[(size_t)b * N_ + i0 + r];
    const int* arow = adj + ((size_t)(b * N_ + i0 + r)) * N_ + jl * 8;

    // MFMA-side ids
    const int lane = tid & 63;
    const int wv = tid >> 6;                      // wave 0..3 -> 32-col slice
    const int lg = lane >> 4;                     // 0..3
    const int ll = lane & 15;
    const unsigned short* hb = hT + ((size_t)b * C_ + wv * 32 + ll) * N_;

    f32x4 acc0 = {0.f, 0.f, 0.f, 0.f}, acc1 = {0.f, 0.f, 0.f, 0.f};

    int4 pf0 = *(const int4*)arow;
    int4 pf1 = *(const int4*)(arow + 4);

    __syncthreads();   // at2s + mrow/lrow init visible

    for (int jt = 0; jt < NJT; ++jt) {
        const int buf = jt & 1;

        // issue hT B-fragment loads for THIS tile early (consumed after barrier)
        short8 vb0[4], vb1[4];
        {
            const unsigned short* hrow = hb + jt * JB + lg * 8;
#pragma unroll
            for (int ks = 0; ks < 4; ++ks) {
                vb0[ks] = *(const short8*)(hrow + ks * 32);
                vb1[ks] = *(const short8*)(hrow + (size_t)16 * N_ + ks * 32);
            }
        }

        int4 A0 = pf0, A1 = pf1;
        if (jt + 1 < NJT) {
            pf0 = *(const int4*)(arow + (jt + 1) * JB);
            pf1 = *(const int4*)(arow + (jt + 1) * JB + 4);
        }
        float4 f0 = *(const float4*)&at2s[jt * JB + jl * 8];
        float4 f1 = *(const float4*)&at2s[jt * JB + jl * 8 + 4];

        // logits: t = a1 + at2[j]; leaky = max(t, 0.2t); masked -> NEG_BIG
        float s[8];
        {
            float t;
            t = a1 + f0.x; t = fmaxf(t, ALPHA * t); s[0] = A0.x > 0 ? t : NEG_BIG;
            t = a1 + f0.y; t = fmaxf(t, ALPHA * t); s[1] = A0.y > 0 ? t : NEG_BIG;
            t = a1 + f0.z; t = fmaxf(t, ALPHA * t); s[2] = A0.z > 0 ? t : NEG_BIG;
            t = a1 + f0.w; t = fmaxf(t, ALPHA * t); s[3] = A0.w > 0 ? t : NEG_BIG;
            t = a1 + f1.x; t = fmaxf(t, ALPHA * t); s[4] = A1.x > 0 ? t : NEG_BIG;
            t = a1 + f1.y; t = fmaxf(t, ALPHA * t); s[5] = A1.y > 0 ? t : NEG_BIG;
            t = a1 + f1.z; t = fmaxf(t, ALPHA * t); s[6] = A1.z > 0 ? t : NEG_BIG;
            t = a1 + f1.w; t = fmaxf(t, ALPHA * t); s[7] = A1.w > 0 ? t : NEG_BIG;
        }
        float tm = fmaxf(fmaxf(fmaxf(s[0], s[1]), fmaxf(s[2], s[3])),
                         fmaxf(fmaxf(s[4], s[5]), fmaxf(s[6], s[7])));
        tm = fmaxf(tm, __shfl_xor(tm, 1));
        tm = fmaxf(tm, __shfl_xor(tm, 2));
        tm = fmaxf(tm, __shfl_xor(tm, 4));
        tm = fmaxf(tm, __shfl_xor(tm, 8));

        const float m_old = mrow[r];           // lockstep within wave: read-before-write
        const float m_new = fmaxf(m_old, tm);

        float p[8];
        float ps = 0.f;
#pragma unroll
        for (int e = 0; e < 8; ++e) { p[e] = __expf(s[e] - m_new); ps += p[e]; }
        ps += __shfl_xor(ps, 1);
        ps += __shfl_xor(ps, 2);
        ps += __shfl_xor(ps, 4);
        ps += __shfl_xor(ps, 8);

        int4 pw;
        pw.x = (int)cvtpk_bf16(p[0], p[1]);
        pw.y = (int)cvtpk_bf16(p[2], p[3]);
        pw.z = (int)cvtpk_bf16(p[4], p[5]);
        pw.w = (int)cvtpk_bf16(p[6], p[7]);
        *(int4*)&P[buf][r][jl * 8] = pw;

        if (jl == 0) {
            const float sc = __expf(m_old - m_new);
            srow[buf][r] = sc;
            mrow[r] = m_new;
            lrow[r] = lrow[r] * sc + ps;
        }
        __syncthreads();   // P[buf], srow[buf] ready; also protects buf reuse at jt+2

        // ---- MFMA phase: this wave does 16(i) x 32(c) x 128(j) ----
        const char* Pb = (const char*)P[buf];
        short8 pa[4];
#pragma unroll
        for (int ks = 0; ks < 4; ++ks)
            pa[ks] = *(const short8*)(Pb + ll * 272 + ks * 64 + lg * 16);

        float4 sc4 = *(const float4*)&srow[buf][lg * 4];
        acc0[0] *= sc4.x; acc0[1] *= sc4.y; acc0[2] *= sc4.z; acc0[3] *= sc4.w;
        acc1[0] *= sc4.x; acc1[1] *= sc4.y; acc1[2] *= sc4.z; acc1[3] *= sc4.w;

#pragma unroll
        for (int ks = 0; ks < 4; ++ks) {
            acc0 = __builtin_amdgcn_mfma_f32_16x16x32_bf16(pa[ks], vb0[ks], acc0, 0, 0, 0);
            acc1 = __builtin_amdgcn_mfma_f32_16x16x32_bf16(pa[ks], vb1[ks], acc1, 0, 0, 0);
        }
    }

    // ---- epilogue: out = acc / l + bias ----
    // lrow final: written in softmax(NJT-1), barrier'd before mfma(NJT-1).
    float4 lw = *(const float4*)&lrow[lg * 4];
    const int c = wv * 32 + ll;
    const float bv0 = bias[c];
    const float bv1 = bias[c + 16];

    float* o = out + ((size_t)(b * N_ + i0 + lg * 4)) * C_ + c;
    o[0 * C_]      = acc0[0] / lw.x + bv0;
    o[1 * C_]      = acc0[1] / lw.y + bv0;
    o[2 * C_]      = acc0[2] / lw.z + bv0;
    o[3 * C_]      = acc0[3] / lw.w + bv0;
    o[0 * C_ + 16] = acc1[0] / lw.x + bv1;
    o[1 * C_ + 16] = acc1[1] / lw.y + bv1;
    o[2 * C_ + 16] = acc1[2] / lw.z + bv1;
    o[3 * C_ + 16] = acc1[3] / lw.w + bv1;
}

extern "C" void kernel_launch(void* const* d_in, const int* in_sizes, int n_in,
                              void* d_out, int out_size, void* d_ws, size_t ws_size,
                              hipStream_t stream) {
    const float* x    = (const float*)d_in[0];
    const int*   adj  = (const int*)d_in[1];
    const float* W    = (const float*)d_in[2];
    const float* a    = (const float*)d_in[3];
    const float* bias = (const float*)d_in[4];
    float* out = (float*)d_out;

    char* ws = (char*)d_ws;
    unsigned short* hT = (unsigned short*)ws;                        // 4 MB bf16 [B,C,N]
    float* at1 = (float*)(ws + (size_t)4 * 1024 * 1024);             // 64 KB
    float* at2 = (float*)(ws + (size_t)4 * 1024 * 1024 + 64 * 1024); // 64 KB

    k1_hidden<<<(B_ * N_) / 64, 256, 0, stream>>>(x, W, a, hT, at1, at2);
    k2_attn<<<B_ * (N_ / IB), 256, 0, stream>>>(adj, hT, at1, at2, bias, out);
}

// Round 3
// 86.926 us; speedup vs baseline: 1.0017x; 1.0017x over previous
//
#include <hip/hip_runtime.h>
#include <hip/hip_bf16.h>

#define ALPHA 0.2f
#define NEG_BIG -1e12f

constexpr int B_ = 8, N_ = 2048, C_ = 128;
constexpr int IB = 16, JB = 128, NJT = N_ / JB;   // 16 j-tiles

typedef __attribute__((ext_vector_type(8))) short short8;
typedef __attribute__((ext_vector_type(8))) unsigned short ushort8;
typedef __attribute__((ext_vector_type(4))) float f32x4;

__device__ __forceinline__ unsigned short f2bf(float f) {
    unsigned int u = __float_as_uint(f);
    u += 0x7fffu + ((u >> 16) & 1u);
    return (unsigned short)(u >> 16);
}

__device__ __forceinline__ unsigned int cvtpk_bf16(float lo, float hi) {
    unsigned int r;
    asm("v_cvt_pk_bf16_f32 %0, %1, %2" : "=v"(r) : "v"(lo), "v"(hi));
    return r;
}

// Workgroup barrier that drains ONLY lgkmcnt (LDS ops) — does NOT drain
// vmcnt, so global prefetches (adj, hT) stay in flight across the barrier.
// This is the T3/T4 counted-wait pattern: __syncthreads() would emit
// s_waitcnt vmcnt(0) and expose full HBM latency every iteration.
__device__ __forceinline__ void barrier_lds_only() {
    asm volatile("s_waitcnt lgkmcnt(0)" ::: "memory");
    __builtin_amdgcn_s_barrier();
}

// ---------------------------------------------------------------------------
// Kernel 1: hidden = x @ W (f32, exact), emit hiddenT bf16 [B, C, N] and
// attn1/attn2 = hidden @ a (f32, exact).  64 rows per block, 256 threads.
// ---------------------------------------------------------------------------
__global__ __launch_bounds__(256) void k1_hidden(
    const float* __restrict__ x, const float* __restrict__ W,
    const float* __restrict__ a, unsigned short* __restrict__ hT,
    float* __restrict__ at1, float* __restrict__ at2)
{
    __shared__ float xs[64][C_];   // 32 KB
    __shared__ float Ws[C_][C_];   // 64 KB
    const int tid = threadIdx.x;
    const int row0 = blockIdx.x * 64;   // global row = b*N + n

    {
        const float4* xsrc = (const float4*)(x + (size_t)row0 * C_);
        float4* xdst = (float4*)&xs[0][0];
        for (int i = tid; i < 64 * C_ / 4; i += 256) xdst[i] = xsrc[i];
        const float4* wsrc = (const float4*)W;
        float4* wdst = (float4*)&Ws[0][0];
        for (int i = tid; i < C_ * C_ / 4; i += 256) wdst[i] = wsrc[i];
    }
    __syncthreads();

    const int tr = tid >> 5, tc = tid & 31;
    const int r0 = tr * 8, c0 = tc * 4;

    float acc[8][4];
#pragma unroll
    for (int i = 0; i < 8; ++i)
#pragma unroll
        for (int j = 0; j < 4; ++j) acc[i][j] = 0.f;

    for (int k = 0; k < C_; k += 4) {
        float4 w0 = *(const float4*)&Ws[k + 0][c0];
        float4 w1 = *(const float4*)&Ws[k + 1][c0];
        float4 w2 = *(const float4*)&Ws[k + 2][c0];
        float4 w3 = *(const float4*)&Ws[k + 3][c0];
#pragma unroll
        for (int rr = 0; rr < 8; ++rr) {
            float4 xv = *(const float4*)&xs[r0 + rr][k];
            acc[rr][0] += xv.x * w0.x + xv.y * w1.x + xv.z * w2.x + xv.w * w3.x;
            acc[rr][1] += xv.x * w0.y + xv.y * w1.y + xv.z * w2.y + xv.w * w3.y;
            acc[rr][2] += xv.x * w0.z + xv.y * w1.z + xv.z * w2.z + xv.w * w3.z;
            acc[rr][3] += xv.x * w0.w + xv.y * w1.w + xv.z * w2.w + xv.w * w3.w;
        }
    }

    // scores: reduce h . a over the 32 tc-lanes (each holds 4 cols)
    float av0[4], av1[4];
#pragma unroll
    for (int cc = 0; cc < 4; ++cc) {
        av0[cc] = a[(c0 + cc) * 2 + 0];
        av1[cc] = a[(c0 + cc) * 2 + 1];
    }
#pragma unroll
    for (int rr = 0; rr < 8; ++rr) {
        float s1 = acc[rr][0] * av0[0] + acc[rr][1] * av0[1] +
                   acc[rr][2] * av0[2] + acc[rr][3] * av0[3];
        float s2 = acc[rr][0] * av1[0] + acc[rr][1] * av1[1] +
                   acc[rr][2] * av1[2] + acc[rr][3] * av1[3];
#pragma unroll
        for (int off = 1; off < 32; off <<= 1) {
            s1 += __shfl_xor(s1, off);
            s2 += __shfl_xor(s2, off);
        }
        if (tc == 0) {
            at1[row0 + r0 + rr] = s1;
            at2[row0 + r0 + rr] = s2;
        }
    }

    // hiddenT bf16: hT[b][c][n]; this thread's 8 rows are consecutive n.
    const int b = row0 >> 11;           // /N_
    const int n0 = row0 & (N_ - 1);
#pragma unroll
    for (int cc = 0; cc < 4; ++cc) {
        ushort8 hv;
#pragma unroll
        for (int rr = 0; rr < 8; ++rr) hv[rr] = f2bf(acc[rr][cc]);
        *(ushort8*)(hT + ((size_t)b * C_ + c0 + cc) * N_ + n0 + r0) = hv;
    }
}

// ---------------------------------------------------------------------------
// Kernel 2: flash-style masked softmax + PV via bf16 MFMA.
// IB=16 rows/block, JB=128 j-tile, 256 threads (4 waves, c-split 32 each).
// Double-buffered P + srow -> ONE lgkm-only barrier per tile; vmcnt never
// drains in the loop so adj/hT prefetches span barriers.
// ---------------------------------------------------------------------------
__global__ __launch_bounds__(256, 4) void k2_attn(
    const int* __restrict__ adj, const unsigned short* __restrict__ hT,
    const float* __restrict__ at1, const float* __restrict__ at2,
    const float* __restrict__ bias, float* __restrict__ out)
{
    __shared__ unsigned short P[2][IB][JB + 8];   // 2 x 16 x 136 bf16 (8.7 KB)
    __shared__ float at2s[N_];                    // 8 KB: whole at2 row for batch
    __shared__ float mrow[IB], lrow[IB], srow[2][IB];

    const int tid = threadIdx.x;
    const int b  = blockIdx.x >> 7;               // N_/IB = 128 i-tiles per batch
    const int i0 = (blockIdx.x & 127) * IB;

    // stage at2[b, :] into LDS (2048 floats)
    {
        const float4* src = (const float4*)(at2 + (size_t)b * N_);
        float4* dst = (float4*)at2s;
        dst[tid]       = src[tid];
        dst[tid + 256] = src[tid + 256];
    }
    if (tid < IB) { mrow[tid] = -3e38f; lrow[tid] = 0.f; }

    // softmax-side ids: 16 threads per row, 8 j each
    const int r  = tid >> 4;                      // 0..15
    const int jl = tid & 15;                      // 0..15
    const float a1 = at1[(size_t)b * N_ + i0 + r];
    const int* arow = adj + ((size_t)(b * N_ + i0 + r)) * N_ + jl * 8;

    // MFMA-side ids
    const int lane = tid & 63;
    const int wv = tid >> 6;                      // wave 0..3 -> 32-col slice
    const int lg = lane >> 4;                     // 0..3
    const int ll = lane & 15;
    const unsigned short* hb = hT + ((size_t)b * C_ + wv * 32 + ll) * N_;

    f32x4 acc0 = {0.f, 0.f, 0.f, 0.f}, acc1 = {0.f, 0.f, 0.f, 0.f};

    __syncthreads();   // at2s + mrow/lrow init visible (once; drain ok here)

    int4 pf0 = *(const int4*)arow;
    int4 pf1 = *(const int4*)(arow + 4);

    for (int jt = 0; jt < NJT; ++jt) {
        const int buf = jt & 1;

        // issue hT B-fragment loads for THIS tile early (consumed after barrier)
        short8 vb0[4], vb1[4];
        {
            const unsigned short* hrow = hb + jt * JB + lg * 8;
#pragma unroll
            for (int ks = 0; ks < 4; ++ks) {
                vb0[ks] = *(const short8*)(hrow + ks * 32);
                vb1[ks] = *(const short8*)(hrow + (size_t)16 * N_ + ks * 32);
            }
        }

        int4 A0 = pf0, A1 = pf1;
        if (jt + 1 < NJT) {
            pf0 = *(const int4*)(arow + (jt + 1) * JB);
            pf1 = *(const int4*)(arow + (jt + 1) * JB + 4);
        }
        float4 f0 = *(const float4*)&at2s[jt * JB + jl * 8];
        float4 f1 = *(const float4*)&at2s[jt * JB + jl * 8 + 4];

        // logits: t = a1 + at2[j]; leaky = max(t, 0.2t); masked -> NEG_BIG
        float s[8];
        {
            float t;
            t = a1 + f0.x; t = fmaxf(t, ALPHA * t); s[0] = A0.x > 0 ? t : NEG_BIG;
            t = a1 + f0.y; t = fmaxf(t, ALPHA * t); s[1] = A0.y > 0 ? t : NEG_BIG;
            t = a1 + f0.z; t = fmaxf(t, ALPHA * t); s[2] = A0.z > 0 ? t : NEG_BIG;
            t = a1 + f0.w; t = fmaxf(t, ALPHA * t); s[3] = A0.w > 0 ? t : NEG_BIG;
            t = a1 + f1.x; t = fmaxf(t, ALPHA * t); s[4] = A1.x > 0 ? t : NEG_BIG;
            t = a1 + f1.y; t = fmaxf(t, ALPHA * t); s[5] = A1.y > 0 ? t : NEG_BIG;
            t = a1 + f1.z; t = fmaxf(t, ALPHA * t); s[6] = A1.z > 0 ? t : NEG_BIG;
            t = a1 + f1.w; t = fmaxf(t, ALPHA * t); s[7] = A1.w > 0 ? t : NEG_BIG;
        }
        float tm = fmaxf(fmaxf(fmaxf(s[0], s[1]), fmaxf(s[2], s[3])),
                         fmaxf(fmaxf(s[4], s[5]), fmaxf(s[6], s[7])));
        tm = fmaxf(tm, __shfl_xor(tm, 1));
        tm = fmaxf(tm, __shfl_xor(tm, 2));
        tm = fmaxf(tm, __shfl_xor(tm, 4));
        tm = fmaxf(tm, __shfl_xor(tm, 8));

        const float m_old = mrow[r];           // lockstep within wave: read-before-write
        const float m_new = fmaxf(m_old, tm);

        float p[8];
        float ps = 0.f;
#pragma unroll
        for (int e = 0; e < 8; ++e) { p[e] = __expf(s[e] - m_new); ps += p[e]; }
        ps += __shfl_xor(ps, 1);
        ps += __shfl_xor(ps, 2);
        ps += __shfl_xor(ps, 4);
        ps += __shfl_xor(ps, 8);

        int4 pw;
        pw.x = (int)cvtpk_bf16(p[0], p[1]);
        pw.y = (int)cvtpk_bf16(p[2], p[3]);
        pw.z = (int)cvtpk_bf16(p[4], p[5]);
        pw.w = (int)cvtpk_bf16(p[6], p[7]);
        *(int4*)&P[buf][r][jl * 8] = pw;

        if (jl == 0) {
            const float sc = __expf(m_old - m_new);
            srow[buf][r] = sc;
            mrow[r] = m_new;
            lrow[r] = lrow[r] * sc + ps;
        }
        barrier_lds_only();   // P[buf], srow[buf] ready; protects buf reuse at jt+2.
                              // lgkm-only: adj/hT prefetches stay in flight.

        // ---- MFMA phase: this wave does 16(i) x 32(c) x 128(j) ----
        const char* Pb = (const char*)P[buf];
        short8 pa[4];
#pragma unroll
        for (int ks = 0; ks < 4; ++ks)
            pa[ks] = *(const short8*)(Pb + ll * 272 + ks * 64 + lg * 16);

        float4 sc4 = *(const float4*)&srow[buf][lg * 4];
        acc0[0] *= sc4.x; acc0[1] *= sc4.y; acc0[2] *= sc4.z; acc0[3] *= sc4.w;
        acc1[0] *= sc4.x; acc1[1] *= sc4.y; acc1[2] *= sc4.z; acc1[3] *= sc4.w;

        __builtin_amdgcn_s_setprio(1);
#pragma unroll
        for (int ks = 0; ks < 4; ++ks) {
            acc0 = __builtin_amdgcn_mfma_f32_16x16x32_bf16(pa[ks], vb0[ks], acc0, 0, 0, 0);
            acc1 = __builtin_amdgcn_mfma_f32_16x16x32_bf16(pa[ks], vb1[ks], acc1, 0, 0, 0);
        }
        __builtin_amdgcn_s_setprio(0);
    }

    // ---- epilogue: out = acc / l + bias ----
    // lrow final: written in softmax(NJT-1), barrier'd before mfma(NJT-1).
    float4 lw = *(const float4*)&lrow[lg * 4];
    const int c = wv * 32 + ll;
    const float bv0 = bias[c];
    const float bv1 = bias[c + 16];

    float* o = out + ((size_t)(b * N_ + i0 + lg * 4)) * C_ + c;
    o[0 * C_]      = acc0[0] / lw.x + bv0;
    o[1 * C_]      = acc0[1] / lw.y + bv0;
    o[2 * C_]      = acc0[2] / lw.z + bv0;
    o[3 * C_]      = acc0[3] / lw.w + bv0;
    o[0 * C_ + 16] = acc1[0] / lw.x + bv1;
    o[1 * C_ + 16] = acc1[1] / lw.y + bv1;
    o[2 * C_ + 16] = acc1[2] / lw.z + bv1;
    o[3 * C_ + 16] = acc1[3] / lw.w + bv1;
}

extern "C" void kernel_launch(void* const* d_in, const int* in_sizes, int n_in,
                              void* d_out, int out_size, void* d_ws, size_t ws_size,
                              hipStream_t stream) {
    const float* x    = (const float*)d_in[0];
    const int*   adj  = (const int*)d_in[1];
    const float* W    = (const float*)d_in[2];
    const float* a    = (const float*)d_in[3];
    const float* bias = (const float*)d_in[4];
    float* out = (float*)d_out;

    char* ws = (char*)d_ws;
    unsigned short* hT = (unsigned short*)ws;                        // 4 MB bf16 [B,C,N]
    float* at1 = (float*)(ws + (size_t)4 * 1024 * 1024);             // 64 KB
    float* at2 = (float*)(ws + (size_t)4 * 1024 * 1024 + 64 * 1024); // 64 KB

    k1_hidden<<<(B_ * N_) / 64, 256, 0, stream>>>(x, W, a, hT, at1, at2);
    k2_attn<<<B_ * (N_ / IB), 256, 0, stream>>>(adj, hT, at1, at2, bias, out);
}